// Round 7
// baseline (993.857 us; speedup 1.0000x reference)
//
#include <hip/hip_runtime.h>
#include <stdint.h>
#include <stddef.h>

typedef unsigned short u16;
typedef __bf16 bf16_t;
typedef bf16_t bf16x8 __attribute__((ext_vector_type(8)));
typedef float f32x4 __attribute__((ext_vector_type(4)));
typedef u16 u16x4 __attribute__((ext_vector_type(4)));

#define N_NODES 50000
#define N_EDGES 65536
#define D_NODE 1024
#define D_HID 1024

// GEMM geometry: 256x256 tile, BK=64, 4 waves (2x2) of 128x128, 128 KiB LDS.
// Rationale (r5 post-mortem): LDS pipe ~85 B/cyc is the co-bottleneck.
// 8 waves of 128x64 read 1536 rows/tile (3x redundancy) = 3012 cyc > MFMA 2483.
// 4 waves of 128x128 read 1024 rows/tile (2x) = 2260 cyc < MFMA 2483.
#define BM 256
#define BK 64
#define BUFE (BM * BK)                 // 16384 elems = 32 KiB per (A or B) buffer
#define LDS_BYTES (4 * BUFE * 2)       // 2 dbuf x (A+B) x 2B = 131072 B

// ---------------- helpers ----------------

__device__ __forceinline__ u16 f2bf(float f) {
  union { float f; uint32_t u; } v; v.f = f;
  uint32_t u = v.u;
  u += 0x7FFF + ((u >> 16) & 1);   // RNE
  return (u16)(u >> 16);
}

typedef __attribute__((address_space(1))) const void GV;
typedef __attribute__((address_space(3))) void LV;

// async global->LDS, 16B per lane; LDS dest = wave-uniform base + lane*16
__device__ __forceinline__ void gll16(const void* g, void* lds_wave_base) {
  __builtin_amdgcn_global_load_lds((GV*)g, (LV*)lds_wave_base, 16, 0, 0);
}

// ---------------- prep kernels ----------------

__global__ void detect_i64_kernel(const int* __restrict__ src, int* __restrict__ flag) {
  if (threadIdx.x == 0 && blockIdx.x == 0) {
    int o = 0;
    for (int i = 1; i < 32; i += 2) o |= src[i];
    *flag = (o == 0) ? 1 : 0;
  }
}

__global__ void cvt_bf16_kernel(const float* __restrict__ in, u16* __restrict__ out, size_t n4) {
  size_t i = (size_t)blockIdx.x * blockDim.x + threadIdx.x;
  if (i >= n4) return;
  float4 v = reinterpret_cast<const float4*>(in)[i];
  u16x4 o;
  o.x = f2bf(v.x); o.y = f2bf(v.y); o.z = f2bf(v.z); o.w = f2bf(v.w);
  reinterpret_cast<u16x4*>(out)[i] = o;
}

// in: [K][N] fp32 row-major  ->  out: [N][K] bf16 row-major
__global__ void transpose_cvt_kernel(const float* __restrict__ in, u16* __restrict__ out,
                                     int K, int N) {
  __shared__ float tile[32][33];
  int n0 = blockIdx.x * 32, k0 = blockIdx.y * 32;
  int tx = threadIdx.x, ty = threadIdx.y;
  #pragma unroll
  for (int i = ty; i < 32; i += 8)
    tile[i][tx] = in[(size_t)(k0 + i) * N + (n0 + tx)];
  __syncthreads();
  #pragma unroll
  for (int i = ty; i < 32; i += 8)
    out[(size_t)(n0 + i) * K + (k0 + tx)] = f2bf(tile[tx][i]);
}

// ---------------- GEMM body ----------------
// 256x256 tile, BK=64, 4 waves (2M x 2N), per-wave 128x128 C via 8x8x2 mfma 16x16x32.
// LDS swizzle (T2, measured 0-conflict): storage k-group = logical ^ (row&7);
//   write side pre-permutes the GLOBAL source k (LDS dest linear, rule #21);
//   read side XORs the fragment k-offset identically.
// Schedule: T3 minimum-2-phase. Per tile u: stage tile u+1 -> other buffer at top
//   (WAR-safe: all waves finished reading it before the previous boundary barrier);
//   then reads+MFMA with compiler-counted lgkm waits (matrix pipe drains async
//   while the wave issues the next read burst); one __syncthreads() per tile
//   (drains the staged loads — a full tile of issue-to-wait cover).
// 1 wave/SIMD (acc=256 VGPR) — deliberate: overlap here is pipe-level, not TLP.
// __launch_bounds__(256,1): explicitly license 512-VGPR/1-wave so the
// occupancy heuristic cannot spill the accumulator (round-3 lesson).

template <bool FIRST>
__device__ __forceinline__ void gemm_body(const u16* __restrict__ Abf,
                                          const int* __restrict__ src,
                                          const int* __restrict__ dst,
                                          const int* __restrict__ is64p,
                                          const u16* __restrict__ Bt,
                                          const float* __restrict__ bias,
                                          u16* __restrict__ hout,
                                          float* __restrict__ fout,
                                          const int K) {
  extern __shared__ __align__(16) u16 lds[];
  u16* const ldsA = lds;                 // [2][BUFE]
  u16* const ldsB = lds + 2 * BUFE;      // [2][BUFE]

  const int t = threadIdx.x;             // 0..255
  const int lane = t & 63;
  const int wave = t >> 6;               // 0..3

  // bijective XCD swizzle: nwg = 1024 (%8==0); nTile fastest so the 4 blocks
  // sharing an A-panel sit consecutively on one XCD.
  const int b = blockIdx.x;
  const int wgid = (b & 7) * 128 + (b >> 3);
  const int bm = (wgid >> 2) * BM;
  const int bn = (wgid & 3) * BM;

  const int wm = (wave >> 1) * 128;   // 2 waves in M
  const int wn = (wave & 1) * 128;    // 2 waves in N

  // ---- staging: chunk qr = rows [qr*32, qr*32+32) x 64 k (4 KiB);
  //      16 gll16/thread/tile (8 A + 8 B); thread t covers row qr*32 + (t>>3),
  //      k-group t&7, with pre-swizzled global k.  row&7 == (t>>3)&7 for all qr
  //      (chunk stride 32 ≡ 0 mod 8) so kswz is thread-uniform across chunks.
  const int srb = t >> 3;                               // 0..31
  const int kswz = (((t & 7) ^ (srb & 7)) << 3);        // elems

  uint32_t aoff[8], doff[8], boff[8];   // byte offsets from Abf / Bt (all < 256 MB)
  if constexpr (FIRST) {
    const int is64 = *is64p;
    #pragma unroll
    for (int qr = 0; qr < 8; ++qr) {
      const int row = qr * 32 + srb;
      const int e = bm + row;
      const int s = is64 ? src[2 * e] : src[e];
      const int d = is64 ? dst[2 * e] : dst[e];
      aoff[qr] = ((uint32_t)s * D_NODE + (uint32_t)kswz) * 2u;
      doff[qr] = ((uint32_t)d * D_NODE + (uint32_t)kswz) * 2u;
      boff[qr] = ((uint32_t)(bn + row) * (uint32_t)K + (uint32_t)kswz) * 2u;
    }
  } else {
    #pragma unroll
    for (int qr = 0; qr < 8; ++qr) {
      const int row = qr * 32 + srb;
      aoff[qr] = ((uint32_t)(bm + row) * (uint32_t)K + (uint32_t)kswz) * 2u;
      boff[qr] = ((uint32_t)(bn + row) * (uint32_t)K + (uint32_t)kswz) * 2u;
    }
  }

  auto stageA = [&](int buf, int qr, int u) {
    uint32_t off;
    if constexpr (FIRST) {
      off = (u < D_NODE / BK) ? aoff[qr] + (uint32_t)(u * BK * 2)
                              : doff[qr] + (uint32_t)((u - D_NODE / BK) * BK * 2);
    } else {
      off = aoff[qr] + (uint32_t)(u * BK * 2);
    }
    gll16((const char*)Abf + off, ldsA + buf * BUFE + qr * 2048 + wave * 512);
  };
  auto stageB = [&](int buf, int qr, int u) {
    gll16((const char*)Bt + (boff[qr] + (uint32_t)(u * BK * 2)),
          ldsB + buf * BUFE + qr * 2048 + wave * 512);
  };
  auto stageGroup = [&](int buf, int u) {
    #pragma unroll
    for (int qr = 0; qr < 8; ++qr) stageA(buf, qr, u);
    #pragma unroll
    for (int qr = 0; qr < 8; ++qr) stageB(buf, qr, u);
  };

  // ---- fragment read setup (carried-over measured-correct formulas) ----
  const int lm = lane & 15;
  const int qw = lane >> 4;
  const int kq8 = qw << 3;                         // 0,8,16,24
  const int swzr = (lm & 7) << 3;                  // row&7 XOR term (elems)
  const int kb0 = kq8 ^ swzr;                      // ks=0 storage offset
  const int kb1 = (32 + kq8) ^ swzr;               // ks=1 storage offset
  const int arow = (wm + lm) * BK;
  const int brow = (wn + lm) * BK;

  f32x4 acc[8][8] = {};

  const int NT = K / BK;

  // ---- prologue: stage tile0 into buf0 ----
  stageGroup(0, 0);
  __syncthreads();

  // ---- main loop: one barrier per K-tile ----
  for (int u = 0; u < NT; ++u) {
    const int cb = u & 1;
    const u16* As_c = ldsA + cb * BUFE;
    const u16* Bs_c = ldsB + cb * BUFE;

    // stage tile u+1 into the other buffer (WAR-safe: its last readers passed
    // the previous boundary barrier)
    if (u + 1 < NT) stageGroup(cb ^ 1, u + 1);

    // ks = 0
    bf16x8 bf0[8];
    #pragma unroll
    for (int j = 0; j < 8; ++j)
      bf0[j] = *reinterpret_cast<const bf16x8*>(Bs_c + brow + j * 1024 + kb0);
    #pragma unroll
    for (int i = 0; i < 8; ++i) {
      bf16x8 a = *reinterpret_cast<const bf16x8*>(As_c + arow + i * 1024 + kb0);
      #pragma unroll
      for (int j = 0; j < 8; ++j)
        acc[i][j] = __builtin_amdgcn_mfma_f32_16x16x32_bf16(a, bf0[j], acc[i][j], 0, 0, 0);
    }

    // ks = 1
    bf16x8 bf1[8];
    #pragma unroll
    for (int j = 0; j < 8; ++j)
      bf1[j] = *reinterpret_cast<const bf16x8*>(Bs_c + brow + j * 1024 + kb1);
    #pragma unroll
    for (int i = 0; i < 8; ++i) {
      bf16x8 a = *reinterpret_cast<const bf16x8*>(As_c + arow + i * 1024 + kb1);
      #pragma unroll
      for (int j = 0; j < 8; ++j)
        acc[i][j] = __builtin_amdgcn_mfma_f32_16x16x32_bf16(a, bf1[j], acc[i][j], 0, 0, 0);
    }

    // boundary: __syncthreads drains vmcnt (staged tile u+1 — full-tile cover)
    // and lgkm (all ds_reads already consumed by MFMAs above), then barriers.
    __syncthreads();
  }

  // ---- epilogue: C/D layout col = lane&15, row = (lane>>4)*4 + rr ----
  const int rq = qw * 4;
  #pragma unroll
  for (int j = 0; j < 8; ++j) {
    const int n = bn + wn + 16 * j + lm;
    const float bj = bias[n];
    #pragma unroll
    for (int i = 0; i < 8; ++i) {
      const int m0 = bm + wm + 16 * i + rq;
      f32x4 c = acc[i][j];
      #pragma unroll
      for (int rr = 0; rr < 4; ++rr) {
        float vv = c[rr] + bj;
        if (FIRST) {
          vv = fmaxf(vv, 0.0f);
          hout[(size_t)(m0 + rr) * D_HID + n] = f2bf(vv);
        } else {
          fout[(size_t)(m0 + rr) * D_HID + n] = vv;
        }
      }
    }
  }
}

__launch_bounds__(256, 1)
__global__ void gemm1_kernel(const u16* __restrict__ Abf, const int* __restrict__ src,
                             const int* __restrict__ dst, const int* __restrict__ is64p,
                             const u16* __restrict__ Bt, const float* __restrict__ bias,
                             u16* __restrict__ hout) {
  gemm_body<true>(Abf, src, dst, is64p, Bt, bias, hout, nullptr, 2 * D_NODE);
}

__launch_bounds__(256, 1)
__global__ void gemm2_kernel(const u16* __restrict__ Abf, const u16* __restrict__ Bt,
                             const float* __restrict__ bias, float* __restrict__ fout) {
  gemm_body<false>(Abf, nullptr, nullptr, nullptr, Bt, bias, nullptr, fout, D_HID);
}

// ---------------- launch ----------------

extern "C" void kernel_launch(void* const* d_in, const int* in_sizes, int n_in,
                              void* d_out, int out_size, void* d_ws, size_t ws_size,
                              hipStream_t stream) {
  const float* node_feats = (const float*)d_in[0];
  const int*   src        = (const int*)d_in[1];
  const int*   dst        = (const int*)d_in[2];
  const float* W1         = (const float*)d_in[3];
  const float* b1         = (const float*)d_in[4];
  const float* W2         = (const float*)d_in[5];
  const float* b2         = (const float*)d_in[6];
  float* out = (float*)d_out;

  // workspace layout (bf16 elements)
  u16* ws = (u16*)d_ws;
  const size_t NODE_E = (size_t)N_NODES * D_NODE;       // 51,200,000
  u16* node_bf = ws;
  u16* W1T = node_bf + NODE_E;                          // [1024][2048]
  u16* W2T = W1T + (size_t)2048 * 1024;                 // [1024][1024]
  u16* h   = W2T + (size_t)1024 * 1024;                 // [65536][1024]
  int* flag = (int*)(h + (size_t)N_EDGES * D_HID);

  static bool attr_set = false;
  if (!attr_set) {
    hipFuncSetAttribute(reinterpret_cast<const void*>(&gemm1_kernel),
                        hipFuncAttributeMaxDynamicSharedMemorySize, LDS_BYTES);
    hipFuncSetAttribute(reinterpret_cast<const void*>(&gemm2_kernel),
                        hipFuncAttributeMaxDynamicSharedMemorySize, LDS_BYTES);
    attr_set = true;
  }

  detect_i64_kernel<<<1, 64, 0, stream>>>(src, flag);

  cvt_bf16_kernel<<<(unsigned)(NODE_E / 4 / 256), 256, 0, stream>>>(node_feats, node_bf, NODE_E / 4);

  transpose_cvt_kernel<<<dim3(1024 / 32, 2048 / 32), dim3(32, 8), 0, stream>>>(W1, W1T, 2048, 1024);
  transpose_cvt_kernel<<<dim3(1024 / 32, 1024 / 32), dim3(32, 8), 0, stream>>>(W2, W2T, 1024, 1024);

  // GEMM1: [65536 x 2048] gathered @ W1T -> relu -> h (bf16)
  gemm1_kernel<<<1024, 256, LDS_BYTES, stream>>>(node_bf, src, dst, flag, W1T, b1, h);

  // GEMM2: h @ W2T + b2 -> out (fp32)
  gemm2_kernel<<<1024, 256, LDS_BYTES, stream>>>(h, W2T, b2, out);
}

// Round 9
// 886.874 us; speedup vs baseline: 1.1206x; 1.1206x over previous
//
#include <hip/hip_runtime.h>
#include <stdint.h>
#include <stddef.h>

typedef unsigned short u16;
typedef __bf16 bf16_t;
typedef bf16_t bf16x8 __attribute__((ext_vector_type(8)));
typedef float f32x4 __attribute__((ext_vector_type(4)));
typedef u16 u16x4 __attribute__((ext_vector_type(4)));

#define N_NODES 50000
#define N_EDGES 65536
#define D_NODE 1024
#define D_HID 1024

// GEMM geometry: 256x128 tile, BK=32, 4 waves (2M x 2N) of 128x64 each.
// Constraint arithmetic (r8 offline audit):
//   - LDS read intensity (WM+WN)/(WM*WN): 64x64 -> 31 B/KFLOP = 106 B/cyc
//     needed at full MFMA rate > 85 B/cyc measured b128 ceiling (m134). BAD.
//   - 128x64 -> 23.4 B/KFLOP = 578 cyc reads < 621 cyc MFMA per block-tile. OK.
//   - acc for 128x64 = 128 VGPR -> ~190 total, fits 256-cap at 2 waves/SIMD.
// 2 blocks/CU (48 KiB LDS each, VGPR 256-cap): desynchronized blocks provide
// the read<->MFMA overlap (m114) that single barrier-locked blocks never had.
#define BM 256
#define BN 128
#define BK 32
#define ABUFE (BM * BK)                // 8192 elems = 16 KiB per buffer
#define BBUFE (BN * BK)                // 4096 elems =  8 KiB per buffer

// ---------------- helpers ----------------

__device__ __forceinline__ u16 f2bf(float f) {
  union { float f; uint32_t u; } v; v.f = f;
  uint32_t u = v.u;
  u += 0x7FFF + ((u >> 16) & 1);   // RNE
  return (u16)(u >> 16);
}

typedef __attribute__((address_space(1))) const void GV;
typedef __attribute__((address_space(3))) void LV;

// async global->LDS, 16B per lane; LDS dest = wave-uniform base + lane*16
__device__ __forceinline__ void gll16(const void* g, void* lds_wave_base) {
  __builtin_amdgcn_global_load_lds((GV*)g, (LV*)lds_wave_base, 16, 0, 0);
}

// ---------------- prep kernels ----------------

__global__ void detect_i64_kernel(const int* __restrict__ src, int* __restrict__ flag) {
  if (threadIdx.x == 0 && blockIdx.x == 0) {
    int o = 0;
    for (int i = 1; i < 32; i += 2) o |= src[i];
    *flag = (o == 0) ? 1 : 0;
  }
}

__global__ void cvt_bf16_kernel(const float* __restrict__ in, u16* __restrict__ out, size_t n4) {
  size_t i = (size_t)blockIdx.x * blockDim.x + threadIdx.x;
  if (i >= n4) return;
  float4 v = reinterpret_cast<const float4*>(in)[i];
  u16x4 o;
  o.x = f2bf(v.x); o.y = f2bf(v.y); o.z = f2bf(v.z); o.w = f2bf(v.w);
  reinterpret_cast<u16x4*>(out)[i] = o;
}

// in: [K][N] fp32 row-major  ->  out: [N][K] bf16 row-major
__global__ void transpose_cvt_kernel(const float* __restrict__ in, u16* __restrict__ out,
                                     int K, int N) {
  __shared__ float tile[32][33];
  int n0 = blockIdx.x * 32, k0 = blockIdx.y * 32;
  int tx = threadIdx.x, ty = threadIdx.y;
  #pragma unroll
  for (int i = ty; i < 32; i += 8)
    tile[i][tx] = in[(size_t)(k0 + i) * N + (n0 + tx)];
  __syncthreads();
  #pragma unroll
  for (int i = ty; i < 32; i += 8)
    out[(size_t)(n0 + i) * K + (k0 + tx)] = f2bf(tile[tx][i]);
}

// ---------------- GEMM body ----------------
// LDS pair-row layout (BK=32 => 64-B rows, two rows per 128-B superrow):
//   superrow R = row>>1 holds rows 2R,2R+1 as 8 16-B slots;
//   slot(row,g) = (((row&1)<<2) | g) ^ (R&7),  g = 8-elem k-group (0..3).
//   Involution both sides; b128 read of 16 consecutive rows at one g hits each
//   16-B slot with exactly 2 lanes per 16-lane group (2-way = free, m136).
// Staging (256 threads): chunk = 128 rows x 32 k = 8 KiB = 2 slices x 4 KiB.
//   Thread t: v = (t&7)^((t>>3)&7) (slice-invariant: slice superrow stride
//   32 ≡ 0 mod 8); covers rows crow=2*(t>>3)+(v>>2) and crow+64, kgroup v&3.
//   LDS dest linear (slice base + wave*512 elems); global src pre-permuted.
// Schedule: 1 barrier per K-tile — stage tile u+1 -> other buffer at top
//   (WAR-safe: previous boundary barrier), 12 b128 frag reads, 32 MFMA,
//   __syncthreads (drains vmcnt: staged loads had the whole tile to fly).
//   Intra-block serial; the SECOND resident block fills the gaps (m114).

template <bool FIRST>
__device__ __forceinline__ void gemm_body(const u16* __restrict__ Abf,
                                          const int* __restrict__ src,
                                          const int* __restrict__ dst,
                                          const int* __restrict__ is64p,
                                          const u16* __restrict__ Bt,
                                          const float* __restrict__ bias,
                                          u16* __restrict__ hout,
                                          float* __restrict__ fout,
                                          const int K) {
  __shared__ __align__(16) u16 ldsA[2][ABUFE];
  __shared__ __align__(16) u16 ldsB[2][BBUFE];

  const int t = threadIdx.x;             // 0..255
  const int lane = t & 63;
  const int wave = t >> 6;               // 0..3

  // bijective XCD swizzle: nwg = 2048 (%8==0), q = 256; n-tile fastest so the
  // 8 blocks sharing an A-panel sit consecutively on one XCD.
  const int b = blockIdx.x;
  const int wgid = (b & 7) * 256 + (b >> 3);
  const int bm = (wgid >> 3) * BM;
  const int bn = (wgid & 7) * BN;

  const int wm = (wave >> 1) * 128;   // 2 waves in M, 128 rows each
  const int wn = (wave & 1) * 64;     // 2 waves in N, 64 cols each

  // ---- staging thread map ----
  const int v = (t & 7) ^ ((t >> 3) & 7);
  const int crow = 2 * (t >> 3) + (v >> 2);        // 0..63
  const uint32_t koff = (uint32_t)(v & 3) * 16u;   // bytes within 64-B k-row

  // per-thread global byte offsets (all < 4 GB)
  uint32_t aoff[4], doff[4] = {0, 0, 0, 0}, boff[2];
  if constexpr (FIRST) {
    const int is64 = *is64p;
    #pragma unroll
    for (int q = 0; q < 4; ++q) {
      const int e = bm + crow + q * 64;
      const int s = is64 ? src[2 * e] : src[e];
      const int d = is64 ? dst[2 * e] : dst[e];
      aoff[q] = (uint32_t)s * (D_NODE * 2u) + koff;
      doff[q] = (uint32_t)d * (D_NODE * 2u) + koff;
    }
  } else {
    #pragma unroll
    for (int q = 0; q < 4; ++q)
      aoff[q] = (uint32_t)(bm + crow + q * 64) * (uint32_t)(K * 2) + koff;
  }
  #pragma unroll
  for (int q = 0; q < 2; ++q)
    boff[q] = (uint32_t)(bn + crow + q * 64) * (uint32_t)(K * 2) + koff;

  const int ldst = wave * 512;   // elems: wave slice base within a 4 KiB slice

  auto stage = [&](int buf, int u) {
    if constexpr (FIRST) {
      uint32_t ka;
      if (u < D_NODE / BK) {
        ka = (uint32_t)(u * BK * 2);
        gll16((const char*)Abf + (aoff[0] + ka), &ldsA[buf][ldst]);
        gll16((const char*)Abf + (aoff[1] + ka), &ldsA[buf][2048 + ldst]);
        gll16((const char*)Abf + (aoff[2] + ka), &ldsA[buf][4096 + ldst]);
        gll16((const char*)Abf + (aoff[3] + ka), &ldsA[buf][6144 + ldst]);
      } else {
        ka = (uint32_t)((u - D_NODE / BK) * BK * 2);
        gll16((const char*)Abf + (doff[0] + ka), &ldsA[buf][ldst]);
        gll16((const char*)Abf + (doff[1] + ka), &ldsA[buf][2048 + ldst]);
        gll16((const char*)Abf + (doff[2] + ka), &ldsA[buf][4096 + ldst]);
        gll16((const char*)Abf + (doff[3] + ka), &ldsA[buf][6144 + ldst]);
      }
    } else {
      const uint32_t ka = (uint32_t)(u * BK * 2);
      gll16((const char*)Abf + (aoff[0] + ka), &ldsA[buf][ldst]);
      gll16((const char*)Abf + (aoff[1] + ka), &ldsA[buf][2048 + ldst]);
      gll16((const char*)Abf + (aoff[2] + ka), &ldsA[buf][4096 + ldst]);
      gll16((const char*)Abf + (aoff[3] + ka), &ldsA[buf][6144 + ldst]);
    }
    const uint32_t kb = (uint32_t)(u * BK * 2);
    gll16((const char*)Bt + (boff[0] + kb), &ldsB[buf][ldst]);
    gll16((const char*)Bt + (boff[1] + kb), &ldsB[buf][2048 + ldst]);
  };

  // ---- fragment read setup (pair-row swizzle, measured-0-conflict family) ----
  const int lm = lane & 15;
  const int qw = lane >> 4;                        // k-group 0..3
  const int slot = ((((lm & 1) << 2) | qw) ^ (lm >> 1)) * 8;       // elems
  const int a_base = (wm / 2 + (lm >> 1)) * 64 + slot;   // + i*512 per 16 rows
  const int b_base = (wn / 2 + (lm >> 1)) * 64 + slot;   // + j*512 per 16 rows

  f32x4 acc[8][4] = {};

  const int NT = K / BK;

  // ---- prologue ----
  stage(0, 0);
  __syncthreads();

  // ---- main loop: 1 barrier per K-tile ----
  for (int u = 0; u < NT; ++u) {
    const int cb = u & 1;

    if (u + 1 < NT) stage(cb ^ 1, u + 1);   // issue early; full tile of cover

    bf16x8 bfr[4], afr[8];
    #pragma unroll
    for (int j = 0; j < 4; ++j)
      bfr[j] = *reinterpret_cast<const bf16x8*>(&ldsB[cb][b_base + j * 512]);
    #pragma unroll
    for (int i = 0; i < 8; ++i)
      afr[i] = *reinterpret_cast<const bf16x8*>(&ldsA[cb][a_base + i * 512]);

    __builtin_amdgcn_s_setprio(1);
    #pragma unroll
    for (int i = 0; i < 8; ++i)
      #pragma unroll
      for (int j = 0; j < 4; ++j)
        acc[i][j] = __builtin_amdgcn_mfma_f32_16x16x32_bf16(afr[i], bfr[j], acc[i][j], 0, 0, 0);
    __builtin_amdgcn_s_setprio(0);

    // __syncthreads waits vmcnt(0)+lgkmcnt(0): staged tile u+1 landed;
    // buffer cb free for restage next iteration.
    __syncthreads();
  }

  // ---- epilogue: C/D layout col = lane&15, row = (lane>>4)*4 + rr ----
  const int rq = qw * 4;
  #pragma unroll
  for (int j = 0; j < 4; ++j) {
    const int n = bn + wn + 16 * j + lm;
    const float bj = bias[n];
    #pragma unroll
    for (int i = 0; i < 8; ++i) {
      const int m0 = bm + wm + 16 * i + rq;
      f32x4 c = acc[i][j];
      #pragma unroll
      for (int rr = 0; rr < 4; ++rr) {
        float vv = c[rr] + bj;
        if (FIRST) {
          vv = fmaxf(vv, 0.0f);
          hout[(size_t)(m0 + rr) * D_HID + n] = f2bf(vv);
        } else {
          fout[(size_t)(m0 + rr) * D_HID + n] = vv;
        }
      }
    }
  }
}

__launch_bounds__(256, 2)
__global__ void gemm1_kernel(const u16* __restrict__ Abf, const int* __restrict__ src,
                             const int* __restrict__ dst, const int* __restrict__ is64p,
                             const u16* __restrict__ Bt, const float* __restrict__ bias,
                             u16* __restrict__ hout) {
  gemm_body<true>(Abf, src, dst, is64p, Bt, bias, hout, nullptr, 2 * D_NODE);
}

__launch_bounds__(256, 2)
__global__ void gemm2_kernel(const u16* __restrict__ Abf, const u16* __restrict__ Bt,
                             const float* __restrict__ bias, float* __restrict__ fout) {
  gemm_body<false>(Abf, nullptr, nullptr, nullptr, Bt, bias, nullptr, fout, D_HID);
}

// ---------------- launch ----------------

extern "C" void kernel_launch(void* const* d_in, const int* in_sizes, int n_in,
                              void* d_out, int out_size, void* d_ws, size_t ws_size,
                              hipStream_t stream) {
  const float* node_feats = (const float*)d_in[0];
  const int*   src        = (const int*)d_in[1];
  const int*   dst        = (const int*)d_in[2];
  const float* W1         = (const float*)d_in[3];
  const float* b1         = (const float*)d_in[4];
  const float* W2         = (const float*)d_in[5];
  const float* b2         = (const float*)d_in[6];
  float* out = (float*)d_out;

  // workspace layout (bf16 elements)
  u16* ws = (u16*)d_ws;
  const size_t NODE_E = (size_t)N_NODES * D_NODE;       // 51,200,000
  u16* node_bf = ws;
  u16* W1T = node_bf + NODE_E;                          // [1024][2048]
  u16* W2T = W1T + (size_t)2048 * 1024;                 // [1024][1024]
  u16* h   = W2T + (size_t)1024 * 1024;                 // [65536][1024]
  int* flag = (int*)(h + (size_t)N_EDGES * D_HID);

  detect_i64_kernel<<<1, 64, 0, stream>>>(src, flag);

  cvt_bf16_kernel<<<(unsigned)(NODE_E / 4 / 256), 256, 0, stream>>>(node_feats, node_bf, NODE_E / 4);

  transpose_cvt_kernel<<<dim3(1024 / 32, 2048 / 32), dim3(32, 8), 0, stream>>>(W1, W1T, 2048, 1024);
  transpose_cvt_kernel<<<dim3(1024 / 32, 1024 / 32), dim3(32, 8), 0, stream>>>(W2, W2T, 1024, 1024);

  // GEMM1: [65536 x 2048] gathered @ W1T -> relu -> h (bf16); grid 256x8 = 2048
  gemm1_kernel<<<2048, 256, 0, stream>>>(node_bf, src, dst, flag, W1T, b1, h);

  // GEMM2: h @ W2T + b2 -> out (fp32); grid 256x8 = 2048
  gemm2_kernel<<<2048, 256, 0, stream>>>(h, W2T, b2, out);
}